// Round 16
// baseline (2382.897 us; speedup 1.0000x reference)
//
#include <hip/hip_runtime.h>

// INSTRUMENTATION ROUND 3 (counter-surfacing, traffic-neutral).
// R13-R15 failed to surface our dispatch in rocprof top-5 (harness fills at
// ~41 us > our 27.7 us) and in-kernel rep probes were compiler-elided.
// This kernel = EXACT R2 structure (fp32, XCD-chunked, NT stores, 27.68 us,
// absmax 0) + block 0 lane 0 sleeps ~60 us via s_sleep (no memory traffic,
// no VALU work, other 16383 blocks untouched). Dispatch dur ~65-70 us ->
// rank 1 -> FETCH_SIZE/WRITE_SIZE finally observable.
// Readout: FETCH >= ~100 MB -> HBM-bound at ceiling w/ refetch -> attack
// fetch next. FETCH <= ~30 MB -> not BW-bound -> latency/serialization
// theory next. Timed result sacrificed this round by design.

#define LVL 8
#define KTOK 1024
#define DIM 512
#define SEQ 4096
#define NB 8
#define CHUNKF 64                  // floats per D-chunk
#define NCHUNK (DIM / CHUNKF)      // 8 chunks, one per XCD

typedef float f4 __attribute__((ext_vector_type(4)));

__global__ __launch_bounds__(256) void multi_embed_kernel(
    const int* __restrict__ x, const float* __restrict__ w, float* __restrict__ out) {
  const int tid   = threadIdx.x;
  const int chunk = blockIdx.x & (NCHUNK - 1);  // XCD-pinned D-chunk
  const int rg    = blockIdx.x >> 3;            // row group, 0..2047
  const int slot  = tid & 15;                   // float4 slot within chunk
  const int rloc  = tid >> 4;                   // 16 rows per block
  const int dbase = chunk * CHUNKF + slot * 4;

  const int row = rg * 16 + rloc;               // flat (n*SEQ + s)
  const int n   = row >> 12;
  const int s   = row & (SEQ - 1);

  const int*   xp = x + n * (LVL * SEQ) + s;
  const float* wp = w + dbase;

  int idx[LVL];
#pragma unroll
  for (int l = 0; l < LVL; ++l) idx[l] = xp[l * SEQ];

  f4 acc = {0.f, 0.f, 0.f, 0.f};
#pragma unroll
  for (int l = 0; l < LVL; ++l)
    acc += *reinterpret_cast<const f4*>(wp + (size_t)(l * KTOK + idx[l]) * DIM);

  __builtin_nontemporal_store(
      acc, reinterpret_cast<f4*>(out + (size_t)row * DIM + dbase));

  // --- instrumentation tail: stretch dispatch duration only -------------
  // block 0's wave 0 sleeps ~60 us (700 * 127 * 64 cy / 2.4 GHz); no memory
  // ops, no lanes active elsewhere. Removed next round.
  if (blockIdx.x == 0 && tid == 0) {
    for (int i = 0; i < 700; ++i) __builtin_amdgcn_s_sleep(127);
  }
}

extern "C" void kernel_launch(void* const* d_in, const int* in_sizes, int n_in,
                              void* d_out, int out_size, void* d_ws, size_t ws_size,
                              hipStream_t stream) {
  const int*   x = (const int*)d_in[0];    // [N, L, S]
  const float* w = (const float*)d_in[1];  // [L, K, D]
  float*     out = (float*)d_out;          // [N, S, D]

  // 32768 rows / 16 per block * 8 chunks = 16384 blocks
  multi_embed_kernel<<<dim3((NB * SEQ / 16) * NCHUNK), dim3(256), 0, stream>>>(x, w, out);
}

// Round 17
// 47.590 us; speedup vs baseline: 50.0709x; 50.0709x over previous
//
#include <hip/hip_runtime.h>

// MultiEmbedding: out[n,s,:] = sum_l weight[l, x[n,l,s], :]
// weight: [L=8, K=1024, D=512] f32, x: [N=8, L=8, S=4096] int32
// out: [N=8, S=4096, D=512] f32
//
// R16 counters: FETCH 12.3 MB, WRITE 64 MB -> 2.9 TB/s at 27.7 us = 46% of
// achievable; NOT BW/fetch/gather/instruction bound. Only never-varied
// factor: fragmented writes (256-512B per block at 2KB stride). Harness
// fills prove contiguous writes run 6.5 TB/s.
// This round: full-row waves. Wave gathers whole row in bf16 (64 lanes x
// 16 B = 1 KB) and writes 2 KB fp32 contiguously; block owns 16 consecutive
// rows -> pure streaming write. No D-chunking (bf16 weight 8.4 MB: ~half
// per-XCD L2, rest L3 -- R16 showed L3 serves gathers fine).

#define LVL 8
#define KTOK 1024
#define DIM 512
#define SEQ 4096
#define NB 8

typedef float f4 __attribute__((ext_vector_type(4)));

__device__ __forceinline__ unsigned f2bf_rne(float f) {
  unsigned u = __float_as_uint(f);
  u += 0x7FFFu + ((u >> 16) & 1u);   // round-to-nearest-even
  return u >> 16;
}

// pack 8 f32 -> 8 bf16 (uint4), one 16-B store per thread
__global__ __launch_bounds__(256) void convert_w_kernel(
    const float* __restrict__ w, unsigned* __restrict__ wb) {
  const int i = blockIdx.x * 256 + threadIdx.x;   // 8 floats per thread
  const float4 a = reinterpret_cast<const float4*>(w)[2 * i];
  const float4 b = reinterpret_cast<const float4*>(w)[2 * i + 1];
  uint4 h;
  h.x = f2bf_rne(a.x) | (f2bf_rne(a.y) << 16);
  h.y = f2bf_rne(a.z) | (f2bf_rne(a.w) << 16);
  h.z = f2bf_rne(b.x) | (f2bf_rne(b.y) << 16);
  h.w = f2bf_rne(b.z) | (f2bf_rne(b.w) << 16);
  reinterpret_cast<uint4*>(wb)[i] = h;
}

__global__ __launch_bounds__(256) void multi_embed_kernel(
    const int* __restrict__ x, const unsigned short* __restrict__ wb,
    float* __restrict__ out) {
  const int wave = threadIdx.x >> 6;        // 0..3
  const int lane = threadIdx.x & 63;        // 8 bf16 (16 B) per lane
  const int rowbase = blockIdx.x * 16;      // 16 consecutive rows per block

#pragma unroll
  for (int it = 0; it < 4; ++it) {
    const int row = rowbase + it * 4 + wave;  // flat (n*SEQ + s)
    const int n   = row >> 12;
    const int s   = row & (SEQ - 1);
    const int* xp = x + n * (LVL * SEQ) + s;

    int idx[LVL];
#pragma unroll
    for (int l = 0; l < LVL; ++l) idx[l] = xp[l * SEQ];

    // full-row gather: 64 lanes x dwordx4 = 1 KB bf16 row
    uint4 g[LVL];
#pragma unroll
    for (int l = 0; l < LVL; ++l)
      g[l] = *reinterpret_cast<const uint4*>(
          wb + (size_t)(l * KTOK + idx[l]) * DIM + lane * 8);

    float a0 = 0.f, a1 = 0.f, a2 = 0.f, a3 = 0.f;
    float a4 = 0.f, a5 = 0.f, a6 = 0.f, a7 = 0.f;
#pragma unroll
    for (int l = 0; l < LVL; ++l) {
      a0 += __uint_as_float(g[l].x << 16);
      a1 += __uint_as_float(g[l].x & 0xFFFF0000u);
      a2 += __uint_as_float(g[l].y << 16);
      a3 += __uint_as_float(g[l].y & 0xFFFF0000u);
      a4 += __uint_as_float(g[l].z << 16);
      a5 += __uint_as_float(g[l].z & 0xFFFF0000u);
      a6 += __uint_as_float(g[l].w << 16);
      a7 += __uint_as_float(g[l].w & 0xFFFF0000u);
    }

    // contiguous write: lane i owns floats [8i, 8i+8) of the 2 KB row
    float* o = out + (size_t)row * DIM + lane * 8;
    f4 lo = {a0, a1, a2, a3};
    f4 hi = {a4, a5, a6, a7};
    __builtin_nontemporal_store(lo, reinterpret_cast<f4*>(o));
    __builtin_nontemporal_store(hi, reinterpret_cast<f4*>(o) + 1);
  }
}

extern "C" void kernel_launch(void* const* d_in, const int* in_sizes, int n_in,
                              void* d_out, int out_size, void* d_ws, size_t ws_size,
                              hipStream_t stream) {
  const int*   x = (const int*)d_in[0];    // [N, L, S]
  const float* w = (const float*)d_in[1];  // [L, K, D]
  float*     out = (float*)d_out;          // [N, S, D]
  unsigned*   wb = (unsigned*)d_ws;        // bf16 weights, 8.4 MB

  // convert f32 -> bf16: 4,194,304 floats / 8 per thread / 256 = 2048 blocks
  convert_w_kernel<<<dim3((LVL * KTOK * DIM) / 8 / 256), dim3(256), 0, stream>>>(w, wb);

  // gather-sum: 32768 rows / 16 rows per block = 2048 blocks
  multi_embed_kernel<<<dim3(NB * SEQ / 16), dim3(256), 0, stream>>>(
      x, (const unsigned short*)wb, out);
}

// Round 18
// 37.949 us; speedup vs baseline: 62.7922x; 1.2541x over previous
//
#include <hip/hip_runtime.h>

// MultiEmbedding: out[n,s,:] = sum_l weight[l, x[n,l,s], :]
// weight: [L=8, K=1024, D=512] f32, x: [N=8, L=8, S=4096] int32
// out: [N=8, S=4096, D=512] f32
//
// R16 counters: FETCH 12.3 MB + WRITE 64 MB at 27.7 us = 2.9 TB/s effective,
// far under the 6.5 TB/s the harness fills sustain. Surviving theory: DRAM
// row-buffer locality -- with 8 D-chunks each XCD writes only 256 B per 2-KB
// output row, so every DRAM row is opened ~8x. This round: 2 chunks of 256
// floats -> each XCD write-visit covers 1 KB contiguous (4x R2 grain), bf16
// half-slice 4.2 MB ~ L2-resident (L3 backstops the slight overflow, cheap
// per R16). Convert tax ~5 us accepted for the probe.

#define LVL 8
#define KTOK 1024
#define DIM 512
#define SEQ 4096
#define NB 8
#define CHUNKF 256                 // floats per D-chunk
#define NCHUNK (DIM / CHUNKF)      // 2 chunks

typedef float f4 __attribute__((ext_vector_type(4)));

__device__ __forceinline__ unsigned f2bf_rne(float f) {
  unsigned u = __float_as_uint(f);
  u += 0x7FFFu + ((u >> 16) & 1u);   // round-to-nearest-even
  return u >> 16;
}

// pack 8 f32 -> 8 bf16 (uint4), one 16-B store per thread
__global__ __launch_bounds__(256) void convert_w_kernel(
    const float* __restrict__ w, unsigned* __restrict__ wb) {
  const int i = blockIdx.x * 256 + threadIdx.x;   // 8 floats per thread
  const float4 a = reinterpret_cast<const float4*>(w)[2 * i];
  const float4 b = reinterpret_cast<const float4*>(w)[2 * i + 1];
  uint4 h;
  h.x = f2bf_rne(a.x) | (f2bf_rne(a.y) << 16);
  h.y = f2bf_rne(a.z) | (f2bf_rne(a.w) << 16);
  h.z = f2bf_rne(b.x) | (f2bf_rne(b.y) << 16);
  h.w = f2bf_rne(b.z) | (f2bf_rne(b.w) << 16);
  reinterpret_cast<uint4*>(wb)[i] = h;
}

__global__ __launch_bounds__(256) void multi_embed_kernel(
    const int* __restrict__ x, const unsigned short* __restrict__ wb,
    float* __restrict__ out) {
  const int tid   = threadIdx.x;
  const int chunk = blockIdx.x & (NCHUNK - 1);   // 2 chunks, alternating XCDs
  const int rgrp  = blockIdx.x >> 1;             // 0..1023
  const int lane5 = tid & 31;                    // 16-B bf16 slot (8 values)
  const int rslot = tid >> 5;                    // 8 row slots per pass
  const int dbase = chunk * CHUNKF + lane5 * 8;  // this thread's 8 floats

  const int rowbase = rgrp * 32;                 // 32 rows per block

#pragma unroll
  for (int it = 0; it < 4; ++it) {
    const int row = rowbase + it * 8 + rslot;    // flat (n*SEQ + s)
    const int n   = row >> 12;
    const int s   = row & (SEQ - 1);
    const int* xp = x + n * (LVL * SEQ) + s;

    int idx[LVL];
#pragma unroll
    for (int l = 0; l < LVL; ++l) idx[l] = xp[l * SEQ];

    // 32 lanes x 16 B = 512 B contiguous bf16 gather per (row, level)
    uint4 g[LVL];
#pragma unroll
    for (int l = 0; l < LVL; ++l)
      g[l] = *reinterpret_cast<const uint4*>(
          wb + (size_t)(l * KTOK + idx[l]) * DIM + dbase);

    float a0 = 0.f, a1 = 0.f, a2 = 0.f, a3 = 0.f;
    float a4 = 0.f, a5 = 0.f, a6 = 0.f, a7 = 0.f;
#pragma unroll
    for (int l = 0; l < LVL; ++l) {
      a0 += __uint_as_float(g[l].x << 16);
      a1 += __uint_as_float(g[l].x & 0xFFFF0000u);
      a2 += __uint_as_float(g[l].y << 16);
      a3 += __uint_as_float(g[l].y & 0xFFFF0000u);
      a4 += __uint_as_float(g[l].z << 16);
      a5 += __uint_as_float(g[l].z & 0xFFFF0000u);
      a6 += __uint_as_float(g[l].w << 16);
      a7 += __uint_as_float(g[l].w & 0xFFFF0000u);
    }

    // 32 lanes x 32 B = 1 KB contiguous fp32 write per (row, chunk)
    float* o = out + (size_t)row * DIM + dbase;
    f4 lo = {a0, a1, a2, a3};
    f4 hi = {a4, a5, a6, a7};
    __builtin_nontemporal_store(lo, reinterpret_cast<f4*>(o));
    __builtin_nontemporal_store(hi, reinterpret_cast<f4*>(o) + 1);
  }
}

extern "C" void kernel_launch(void* const* d_in, const int* in_sizes, int n_in,
                              void* d_out, int out_size, void* d_ws, size_t ws_size,
                              hipStream_t stream) {
  const int*   x = (const int*)d_in[0];    // [N, L, S]
  const float* w = (const float*)d_in[1];  // [L, K, D]
  float*     out = (float*)d_out;          // [N, S, D]
  unsigned*   wb = (unsigned*)d_ws;        // bf16 weights, 8.4 MB

  // convert f32 -> bf16: 4,194,304 floats / 8 per thread / 256 = 2048 blocks
  convert_w_kernel<<<dim3((LVL * KTOK * DIM) / 8 / 256), dim3(256), 0, stream>>>(w, wb);

  // gather-sum: (32768 rows / 32 per block) * 2 chunks = 2048 blocks
  multi_embed_kernel<<<dim3((NB * SEQ / 32) * NCHUNK), dim3(256), 0, stream>>>(
      x, (const unsigned short*)wb, out);
}

// Round 19
// 27.679 us; speedup vs baseline: 86.0902x; 1.3710x over previous
//
#include <hip/hip_runtime.h>

// MultiEmbedding: out[n,s,:] = sum_l weight[l, x[n,l,s], :]
// weight: [L=8, K=1024, D=512] f32, x: [N=8, L=8, S=4096] int32
// out: [N=8, S=4096, D=512] f32
//
// FINAL (champion config, = round 2/14 structure, 27.68 us measured):
//   - D split into 8 chunks of 64 floats; chunk = blockIdx%8 pins each chunk
//     to one XCD (round-robin dispatch) -> 2 MiB weight slice resident in
//     that XCD's 4 MiB L2. R16 counters confirm: FETCH 12.3 MB (minimal),
//     WRITE 64 MB (exact).
//   - NT stores (plain stores: +9%, R13).
//   - fp32 exact (absmax 0.0); bf16 variants saved no time (R6/R8/R12).
// Plateau evidence (R5-R18): gather bytes/lines/instructions halved, MLP
// doubled, write grain 256B..2KB, block shapes varied -- all land 27.7-34 us.
// 80 MB HBM @ 2.9 TB/s effective is this op's empirical floor here.

#define LVL 8
#define KTOK 1024
#define DIM 512
#define SEQ 4096
#define NB 8
#define CHUNKF 64                  // floats per D-chunk
#define NCHUNK (DIM / CHUNKF)      // 8 chunks, one per XCD

typedef float f4 __attribute__((ext_vector_type(4)));

__global__ __launch_bounds__(256) void multi_embed_kernel(
    const int* __restrict__ x, const float* __restrict__ w, float* __restrict__ out) {
  const int tid   = threadIdx.x;
  const int chunk = blockIdx.x & (NCHUNK - 1);  // XCD-pinned D-chunk
  const int rg    = blockIdx.x >> 3;            // row group, 0..2047
  const int slot  = tid & 15;                   // float4 slot within chunk
  const int rloc  = tid >> 4;                   // 16 rows per block
  const int dbase = chunk * CHUNKF + slot * 4;

  const int row = rg * 16 + rloc;               // flat (n*SEQ + s)
  const int n   = row >> 12;
  const int s   = row & (SEQ - 1);

  const int*   xp = x + n * (LVL * SEQ) + s;
  const float* wp = w + dbase;

  int idx[LVL];
#pragma unroll
  for (int l = 0; l < LVL; ++l) idx[l] = xp[l * SEQ];

  f4 acc = {0.f, 0.f, 0.f, 0.f};
#pragma unroll
  for (int l = 0; l < LVL; ++l)
    acc += *reinterpret_cast<const f4*>(wp + (size_t)(l * KTOK + idx[l]) * DIM);

  __builtin_nontemporal_store(
      acc, reinterpret_cast<f4*>(out + (size_t)row * DIM + dbase));
}

extern "C" void kernel_launch(void* const* d_in, const int* in_sizes, int n_in,
                              void* d_out, int out_size, void* d_ws, size_t ws_size,
                              hipStream_t stream) {
  const int*   x = (const int*)d_in[0];    // [N, L, S]
  const float* w = (const float*)d_in[1];  // [L, K, D]
  float*     out = (float*)d_out;          // [N, S, D]

  // 32768 rows / 16 per block * 8 chunks = 16384 blocks
  multi_embed_kernel<<<dim3((NB * SEQ / 16) * NCHUNK), dim3(256), 0, stream>>>(x, w, out);
}